// Round 6
// baseline (120.903 us; speedup 1.0000x reference)
//
#include <hip/hip_runtime.h>

// LogicGatedSNN:
//   w       = ternary(synapse_states) in {-1,0,+1}
//   current = spike @ w.T                       [B, OUT]
//   eff     = current * (refractory_count<=0)   (refr>0 => gated to 0)
//   v       = 0.7*mp + eff
//   spikes  = (v >= thr) ? 1 : 0
//
// Dataset reality: refractory_count = 2*U[0,1) > 0 for (almost surely) every
// output neuron, so eff == 0 everywhere and the output is a broadcast of the
// per-column base value (0.7*mp[o] >= thr[o]). Strategy:
//   k_fill: write base value to the whole [B, OUT] output (16B nontemporal
//           streaming stores — this IS the roofline: 67 MB mandatory writes).
//   k_col : one block per output column; exits immediately if refr[o] > 0
//           (the ~always case). Otherwise computes the exact ternary dot
//           (integer sums, exact in fp32) and overwrites that column.
// Stream order serializes k_fill -> k_col, so the overwrite is race-free.

// Native clang vector type: __builtin_nontemporal_store requires a vector of
// float, not HIP's float4 class type.
typedef float v4f __attribute__((ext_vector_type(4)));

__global__ __launch_bounds__(256) void k_fill(
    float* __restrict__ out,
    const float* __restrict__ mp,
    const float* __restrict__ thr,
    int total4, int out4mask)
{
    const v4f* mp4 = reinterpret_cast<const v4f*>(mp);
    const v4f* th4 = reinterpret_cast<const v4f*>(thr);
    v4f* o4 = reinterpret_cast<v4f*>(out);
    const int idx    = blockIdx.x * blockDim.x + threadIdx.x;
    const int stride = gridDim.x * blockDim.x;
    // Host guarantees stride % (out4mask+1) == 0, so this thread's column
    // group is invariant across its grid-stride iterations -> hoist the
    // base computation out of the store loop.
    const int c = idx & out4mask;
    const v4f m = mp4[c];
    const v4f t = th4[c];
    v4f base;
    base.x = (0.7f * m.x >= t.x) ? 1.0f : 0.0f;
    base.y = (0.7f * m.y >= t.y) ? 1.0f : 0.0f;
    base.z = (0.7f * m.z >= t.z) ? 1.0f : 0.0f;
    base.w = (0.7f * m.w >= t.w) ? 1.0f : 0.0f;
    for (int v = idx; v < total4; v += stride)
        __builtin_nontemporal_store(base, &o4[v]);   // global_store_dwordx4 nt
}

// Rare path: exact per-column recompute for non-refractory columns.
// spike in {0,1}, w in {-1,0,+1}: all partial sums are integers |s| <= IN,
// exact in fp32 regardless of order -> bit-identical compare vs reference.
__global__ __launch_bounds__(256) void k_col(
    const float* __restrict__ spike,
    const float* __restrict__ syn,
    const float* __restrict__ mp,
    const float* __restrict__ thr,
    const float* __restrict__ refr,
    float* __restrict__ out,
    int Bv, int IN, int OUT)
{
    const int o = blockIdx.x;
    if (refr[o] > 0.0f) return;   // refractory: k_fill's value is final

    extern __shared__ float w_s[];            // IN floats (8 KB for IN=2048)
    for (int i = threadIdx.x; i < IN; i += blockDim.x) {
        float s = syn[(size_t)o * IN + i];
        w_s[i] = (s > 1.0f) ? 1.0f : ((s < -1.0f) ? -1.0f : 0.0f);
    }
    __syncthreads();

    const float mpo = 0.7f * mp[o];
    const float th  = thr[o];
    for (int row0 = 0; row0 < Bv; row0 += blockDim.x) {
        const int b = row0 + threadIdx.x;
        if (b >= Bv) break;
        const float4* sp = reinterpret_cast<const float4*>(spike + (size_t)b * IN);
        float acc = 0.0f;
        for (int i = 0; i < IN / 4; ++i) {
            float4 v = sp[i];   // w_s reads are wave-uniform -> LDS broadcast, conflict-free
            acc += v.x * w_s[4*i+0] + v.y * w_s[4*i+1]
                 + v.z * w_s[4*i+2] + v.w * w_s[4*i+3];
        }
        out[(size_t)b * OUT + o] = (mpo + acc >= th) ? 1.0f : 0.0f;
    }
}

extern "C" void kernel_launch(void* const* d_in, const int* in_sizes, int n_in,
                              void* d_out, int out_size, void* d_ws, size_t ws_size,
                              hipStream_t stream) {
    const float* spike = (const float*)d_in[0];
    const float* syn   = (const float*)d_in[1];
    const float* mp    = (const float*)d_in[2];
    const float* thr   = (const float*)d_in[3];
    const float* refr  = (const float*)d_in[4];
    float* out = (float*)d_out;

    const int OUT  = in_sizes[2];          // 2048
    const int IN   = in_sizes[1] / OUT;    // 2048
    const int Bv   = in_sizes[0] / IN;     // 8192
    const int OUT4 = OUT / 4;              // 512 (power of two)
    const int total4 = out_size / 4;       // 4,194,304 float4 stores

    // 2048 blocks * 256 threads = 524288 = 1024 * OUT4 -> column-invariant
    // grid-stride in k_fill; ~8 float4 stores per thread.
    k_fill<<<dim3(2048), dim3(256), 0, stream>>>(out, mp, thr, total4, OUT4 - 1);

    // One block per output column; all exit immediately on this dataset.
    k_col<<<dim3(OUT), dim3(256), IN * sizeof(float), stream>>>(
        spike, syn, mp, thr, refr, out, Bv, IN, OUT);
}

// Round 8
// 119.695 us; speedup vs baseline: 1.0101x; 1.0101x over previous
//
#include <hip/hip_runtime.h>

// LogicGatedSNN:
//   w       = ternary(synapse_states) in {-1,0,+1}
//   current = spike @ w.T                       [B, OUT]
//   eff     = current * (refractory_count<=0)   (refr>0 => gated to 0)
//   v       = 0.7*mp + eff
//   spikes  = (v >= thr) ? 1 : 0
//
// Dataset reality (confirmed on HW round 6, absmax=0.0): refractory_count =
// 2*U[0,1) > 0 for every output neuron, so eff == 0 everywhere and the output
// is a broadcast of the per-column base value (0.7*mp[o] >= thr[o]).
//   k_fill: write base value to the whole [B, OUT] output. REGULAR
//           (cache-allocating) float4 stores, not nontemporal — d_out (67 MB)
//           fits the 256 MB Infinity Cache, so cached stores complete at L3
//           rate and the HBM writeback drains after kernel retire. nt forced
//           the slower HBM path.
//   k_col : one block per output column; exits immediately if refr[o] > 0
//           (the ~always case). Otherwise computes the exact ternary dot
//           (integer sums, exact in fp32) and overwrites that column.
// Stream order serializes k_fill -> k_col, so the overwrite is race-free.

typedef float v4f __attribute__((ext_vector_type(4)));

__global__ __launch_bounds__(256) void k_fill(
    float* __restrict__ out,
    const float* __restrict__ mp,
    const float* __restrict__ thr,
    int total4, int out4mask)
{
    const v4f* mp4 = reinterpret_cast<const v4f*>(mp);
    const v4f* th4 = reinterpret_cast<const v4f*>(thr);
    v4f* o4 = reinterpret_cast<v4f*>(out);
    const int idx    = blockIdx.x * blockDim.x + threadIdx.x;
    const int stride = gridDim.x * blockDim.x;
    // stride % (out4mask+1) == 0 (host guarantees), so this thread's column
    // group is invariant across its grid-stride iterations -> hoist the
    // base computation out of the store loop.
    const int c = idx & out4mask;
    const v4f m = mp4[c];
    const v4f t = th4[c];
    v4f base;
    base.x = (0.7f * m.x >= t.x) ? 1.0f : 0.0f;
    base.y = (0.7f * m.y >= t.y) ? 1.0f : 0.0f;
    base.z = (0.7f * m.z >= t.z) ? 1.0f : 0.0f;
    base.w = (0.7f * m.w >= t.w) ? 1.0f : 0.0f;
    for (int v = idx; v < total4; v += stride)
        o4[v] = base;              // cached global_store_dwordx4 (L3-allocating)
}

// Rare path: exact per-column recompute for non-refractory columns.
// spike in {0,1}, w in {-1,0,+1}: all partial sums are integers |s| <= IN,
// exact in fp32 regardless of order -> bit-identical compare vs reference.
__global__ __launch_bounds__(256) void k_col(
    const float* __restrict__ spike,
    const float* __restrict__ syn,
    const float* __restrict__ mp,
    const float* __restrict__ thr,
    const float* __restrict__ refr,
    float* __restrict__ out,
    int Bv, int IN, int OUT)
{
    const int o = blockIdx.x;
    if (refr[o] > 0.0f) return;   // refractory: k_fill's value is final

    extern __shared__ float w_s[];            // IN floats (8 KB for IN=2048)
    for (int i = threadIdx.x; i < IN; i += blockDim.x) {
        float s = syn[(size_t)o * IN + i];
        w_s[i] = (s > 1.0f) ? 1.0f : ((s < -1.0f) ? -1.0f : 0.0f);
    }
    __syncthreads();

    const float mpo = 0.7f * mp[o];
    const float th  = thr[o];
    for (int row0 = 0; row0 < Bv; row0 += blockDim.x) {
        const int b = row0 + threadIdx.x;
        if (b >= Bv) break;
        const float4* sp = reinterpret_cast<const float4*>(spike + (size_t)b * IN);
        float acc = 0.0f;
        for (int i = 0; i < IN / 4; ++i) {
            float4 v = sp[i];   // w_s reads are wave-uniform -> LDS broadcast, conflict-free
            acc += v.x * w_s[4*i+0] + v.y * w_s[4*i+1]
                 + v.z * w_s[4*i+2] + v.w * w_s[4*i+3];
        }
        out[(size_t)b * OUT + o] = (mpo + acc >= th) ? 1.0f : 0.0f;
    }
}

extern "C" void kernel_launch(void* const* d_in, const int* in_sizes, int n_in,
                              void* d_out, int out_size, void* d_ws, size_t ws_size,
                              hipStream_t stream) {
    const float* spike = (const float*)d_in[0];
    const float* syn   = (const float*)d_in[1];
    const float* mp    = (const float*)d_in[2];
    const float* thr   = (const float*)d_in[3];
    const float* refr  = (const float*)d_in[4];
    float* out = (float*)d_out;

    const int OUT  = in_sizes[2];          // 2048
    const int IN   = in_sizes[1] / OUT;    // 2048
    const int Bv   = in_sizes[0] / IN;     // 8192
    const int OUT4 = OUT / 4;              // 512 (power of two)
    const int total4 = out_size / 4;       // 4,194,304 float4 stores

    // 2048 blocks * 256 threads = 524288 = 1024 * OUT4 -> column-invariant
    // grid-stride in k_fill; ~8 float4 stores per thread.
    k_fill<<<dim3(2048), dim3(256), 0, stream>>>(out, mp, thr, total4, OUT4 - 1);

    // One block per output column; all exit immediately on this dataset.
    k_col<<<dim3(OUT), dim3(256), IN * sizeof(float), stream>>>(
        spike, syn, mp, thr, refr, out, Bv, IN, OUT);
}